// Round 1
// baseline (280.320 us; speedup 1.0000x reference)
//
#include <hip/hip_runtime.h>

// Problem constants (from reference):
// B=16384 samples, F=256 features, T=512 trees, D=7 internal levels (after root), C=4 outputs
#define BB 16384
#define FF 256
#define TT 512
#define DD 7
#define CC 4

// Block = 256 threads. Block owns S samples (x rows resident in LDS for the whole
// kernel) and iterates over T/G tree tiles of G trees; each tile's (feat,bias)
// node data is staged packed (int2) into LDS so every traversal gather is an LDS
// access, never a random global access. Each thread interleaves NP = S*G/256
// independent tree traversals for ILP (hides LDS latency at 4 waves/CU).
template<int S, int G>
__global__ __launch_bounds__(256, 1)
void tree_traverse_kernel(const float* __restrict__ x,
                          const int*   __restrict__ root_nodes,
                          const float* __restrict__ root_biases,
                          const int*   __restrict__ nodes_flat,
                          const float* __restrict__ biases_flat,
                          const float* __restrict__ leaf_nodes,
                          float*       __restrict__ out)
{
    constexpr int NP      = (S * G) / 256;  // (sample,tree) pairs per thread per tile
    constexpr int NTILES  = TT / G;
    constexpr int TSTRIDE = 256 / S;        // tree-index stride between a thread's trees

    extern __shared__ char smem[];
    float* x_s    = (float*)smem;                              // S*FF floats
    int2*  tree_s = (int2*)(smem + (size_t)S * FF * 4);        // 254*G packed entries

    const int tid   = threadIdx.x;
    const int s     = tid % S;        // local sample this thread serves
    const int gbase = tid / S;        // base tree offset within tile
    const int s0    = blockIdx.x * S; // first global sample of this block
    const int xbase = s * FF;

    // ---- stage x rows (once per block), coalesced float4 ----
    {
        const float4* xg = (const float4*)(x + (size_t)s0 * FF);
        float4* xs = (float4*)x_s;
        constexpr int NV = S * FF / 4;   // float4 count (divisible by 256 for S=32/64)
        #pragma unroll
        for (int i = 0; i < NV / 256; ++i)
            xs[tid + i * 256] = xg[tid + i * 256];
    }

    float a0 = 0.f, a1 = 0.f, a2 = 0.f, a3 = 0.f;

    for (int tile = 0; tile < NTILES; ++tile) {
        const int t0 = tile * G;

        __syncthreads();  // previous tile's traversal reads done (also orders x staging)

        // ---- stage tree tile: levels 1..D, trees [t0, t0+G) are contiguous per level ----
        {
            int lbase = 0;
            #pragma unroll
            for (int l = 1; l <= DD; ++l) {
                const int cnt  = G << l;
                const int goff = TT * ((1 << l) - 2) + (t0 << l);
                for (int i = tid; i < cnt; i += 256) {
                    tree_s[lbase + i] = make_int2(nodes_flat[goff + i],
                                                  __float_as_int(biases_flat[goff + i]));
                }
                lbase += cnt;
            }
        }
        __syncthreads();

        // ---- root level (uniform address per wave for S=64 -> broadcast load) ----
        int p[NP];
        #pragma unroll
        for (int k = 0; k < NP; ++k) {
            const int t = t0 + gbase + TSTRIDE * k;
            const int rn   = root_nodes[t];
            const float rb = root_biases[t];
            p[k] = (x_s[xbase + rn] < rb) ? 1 : 0;
        }

        // ---- levels 1..D: NP independent chains per level for ILP ----
        #pragma unroll
        for (int l = 1; l <= DD; ++l) {
            const int lvl = (G << l) - 2 * G;  // LDS base of this level in the tile
            #pragma unroll
            for (int k = 0; k < NP; ++k) {
                const int g = gbase + TSTRIDE * k;
                const int2 nb  = tree_s[lvl + (g << l) + p[k]];
                const float ft = x_s[xbase + nb.x];
                p[k] = 2 * p[k] + ((ft < __int_as_float(nb.y)) ? 1 : 0);
            }
        }

        // ---- leaf gather (global, L2-resident 2 MB) + accumulate ----
        #pragma unroll
        for (int k = 0; k < NP; ++k) {
            const int t = t0 + gbase + TSTRIDE * k;
            const float4 lf = ((const float4*)leaf_nodes)[(t << (DD + 1)) + p[k]];
            a0 += lf.x; a1 += lf.y; a2 += lf.z; a3 += lf.w;
        }
    }

    // ---- cross-thread reduction: 256/S partials per sample, overlay on x_s ----
    __syncthreads();
    float* red = x_s;               // 256*4 floats = 4 KB, fits in x_s region
    red[tid * 4 + 0] = a0;
    red[tid * 4 + 1] = a1;
    red[tid * 4 + 2] = a2;
    red[tid * 4 + 3] = a3;
    __syncthreads();
    if (tid < S) {
        float o0 = 0.f, o1 = 0.f, o2 = 0.f, o3 = 0.f;
        #pragma unroll
        for (int r = 0; r < 256 / S; ++r) {
            const int j = (tid + r * S) * 4;
            o0 += red[j + 0]; o1 += red[j + 1]; o2 += red[j + 2]; o3 += red[j + 3];
        }
        ((float4*)out)[s0 + tid] = make_float4(o0, o1, o2, o3);
    }
}

extern "C" void kernel_launch(void* const* d_in, const int* in_sizes, int n_in,
                              void* d_out, int out_size, void* d_ws, size_t ws_size,
                              hipStream_t stream) {
    const float* x           = (const float*)d_in[0];
    const int*   root_nodes  = (const int*)  d_in[1];
    const float* root_biases = (const float*)d_in[2];
    // d_in[3] = tree_indices = 2*t, folded into the index math
    const int*   nodes_flat  = (const int*)  d_in[4];
    const float* biases_flat = (const float*)d_in[5];
    const float* leaf_nodes  = (const float*)d_in[6];
    float*       out         = (float*)d_out;

    constexpr int BIG_LDS   = 64 * FF * 4 + 254 * 32 * 8;  // 65536 + 65024 = 130560 B
    constexpr int SMALL_LDS = 32 * FF * 4 + 254 * 16 * 8;  // 32768 + 32512 = 65280 B

    int dev = 0;
    (void)hipGetDevice(&dev);                       // host query: graph-capture safe
    int maxlds = 0;
    (void)hipDeviceGetAttribute(&maxlds, hipDeviceAttributeMaxSharedMemoryPerBlock, dev);

    if (maxlds >= BIG_LDS) {
        // idempotent, non-stream, harmless if a no-op on ROCm
        (void)hipFuncSetAttribute(reinterpret_cast<const void*>(&tree_traverse_kernel<64, 32>),
                                  hipFuncAttributeMaxDynamicSharedMemorySize, BIG_LDS);
        tree_traverse_kernel<64, 32><<<BB / 64, 256, BIG_LDS, stream>>>(
            x, root_nodes, root_biases, nodes_flat, biases_flat, leaf_nodes, out);
    } else {
        tree_traverse_kernel<32, 16><<<BB / 32, 256, SMALL_LDS, stream>>>(
            x, root_nodes, root_biases, nodes_flat, biases_flat, leaf_nodes, out);
    }
}

// Round 2
// 117.583 us; speedup vs baseline: 2.3840x; 2.3840x over previous
//
#include <hip/hip_runtime.h>

// B=16384 samples, F=256 features, T=512 trees, D=7 levels below root, C=4 outputs
#define BB 16384
#define FF 256
#define TT 512
#define DD 7

// LDS x row stride (floats), padded so bank = (s + f) % 32: shared-feature
// reads (root / low levels) spread across all banks instead of 64-way conflict.
#define XS 257

constexpr int S_   = 32;        // samples per block (x rows in LDS: 32*257*4 = 32.9 KB)
constexpr int NT_  = 512;       // threads per block -> 8 waves; 2 blocks/CU = 16 waves/CU
constexpr int NTG  = NT_ / S_;  // 16 tree-groups per block
constexpr int TPT  = TT / NTG;  // 32 trees per thread
constexpr int NP   = 8;         // concurrent tree chains per thread (ILP)
constexpr int NJ   = TPT / NP;  // 4 outer iterations
constexpr int NPACK = TT * ((1 << (DD + 1)) - 2);  // 130048 packed nodes

// Pre-pack (feat, bias) into int2 so the traversal does ONE global gather per step.
__global__ void pack_nodes_kernel(const int* __restrict__ nf,
                                  const float* __restrict__ bf,
                                  int2* __restrict__ tp, int n) {
    int i = blockIdx.x * 256 + threadIdx.x;
    if (i < n) tp[i] = make_int2(nf[i], __float_as_int(bf[i]));
}

// Trees are read straight from L2 (nodes: 1 MB, L2-resident; lanes of a wave
// share the tree, so a level-l gather spans <= 2^l consecutive entries).
// x lives in LDS with padded stride. No barriers inside the main loop.
template<bool PACKED>
__global__ __launch_bounds__(NT_, 4)
void tree_traverse_kernel(const float* __restrict__ x,
                          const int*   __restrict__ root_nodes,
                          const float* __restrict__ root_biases,
                          const int*   __restrict__ nodes_flat,
                          const float* __restrict__ biases_flat,
                          const float* __restrict__ leaf_nodes,
                          const int2*  __restrict__ tp,
                          float*       __restrict__ out)
{
    __shared__ float x_s[S_ * XS];   // 32 rows, stride 257

    const int tid = threadIdx.x;
    const int s   = tid & (S_ - 1);   // lane's sample within block
    const int tg  = tid / S_;         // tree-group (16 per block)
    const int s0  = blockIdx.x * S_;

    // ---- stage x rows: float4 global loads, scalar LDS stores (padded stride) ----
    {
        const float4* xg = (const float4*)(x + (size_t)s0 * FF);
        const int r = tid >> 4;        // row 0..31
        const int v = tid & 15;        // covers 16 of 64 float4 per row
        #pragma unroll
        for (int c = 0; c < 4; ++c) {
            const float4 q = xg[r * (FF / 4) + v + 16 * c];
            const int base = r * XS + (v + 16 * c) * 4;
            x_s[base + 0] = q.x; x_s[base + 1] = q.y;
            x_s[base + 2] = q.z; x_s[base + 3] = q.w;
        }
    }
    __syncthreads();

    const int xb = s * XS;
    const float4* leaf4 = (const float4*)leaf_nodes;
    float a0 = 0.f, a1 = 0.f, a2 = 0.f, a3 = 0.f;

    #pragma unroll 1
    for (int j = 0; j < NJ; ++j) {
        const int tbase = tg * TPT + j * NP;   // first of NP trees this iteration

        // ---- root level ----
        int p[NP];
        #pragma unroll
        for (int k = 0; k < NP; ++k) {
            const int t  = tbase + k;
            const int rn = root_nodes[t];
            const float rb = root_biases[t];
            p[k] = (x_s[xb + rn] < rb) ? 1 : 0;
        }

        // ---- levels 1..D: NP independent chains ----
        #pragma unroll
        for (int l = 1; l <= DD; ++l) {
            const int lbase = TT * ((1 << l) - 2);
            #pragma unroll
            for (int k = 0; k < NP; ++k) {
                const int t = tbase + k;
                const int e = lbase + (t << l) + p[k];
                int   fi; float bi;
                if (PACKED) {
                    const int2 nb = tp[e];
                    fi = nb.x; bi = __int_as_float(nb.y);
                } else {
                    fi = nodes_flat[e]; bi = biases_flat[e];
                }
                const float ft = x_s[xb + fi];
                p[k] = 2 * p[k] + ((ft < bi) ? 1 : 0);
            }
        }

        // ---- leaf gather (L2) + accumulate ----
        #pragma unroll
        for (int k = 0; k < NP; ++k) {
            const int t = tbase + k;
            const float4 lf = leaf4[(t << (DD + 1)) + p[k]];
            a0 += lf.x; a1 += lf.y; a2 += lf.z; a3 += lf.w;
        }
    }

    // ---- reduce 16 tree-group partials per sample (overlay on x_s) ----
    __syncthreads();
    float* red = x_s;     // need 512*4 = 2048 floats <= 8224 available
    red[tid * 4 + 0] = a0; red[tid * 4 + 1] = a1;
    red[tid * 4 + 2] = a2; red[tid * 4 + 3] = a3;
    __syncthreads();
    if (tid < S_) {
        float o0 = 0.f, o1 = 0.f, o2 = 0.f, o3 = 0.f;
        #pragma unroll
        for (int g = 0; g < NTG; ++g) {
            const int jj = (g * S_ + tid) * 4;
            o0 += red[jj + 0]; o1 += red[jj + 1];
            o2 += red[jj + 2]; o3 += red[jj + 3];
        }
        ((float4*)out)[s0 + tid] = make_float4(o0, o1, o2, o3);
    }
}

extern "C" void kernel_launch(void* const* d_in, const int* in_sizes, int n_in,
                              void* d_out, int out_size, void* d_ws, size_t ws_size,
                              hipStream_t stream) {
    const float* x           = (const float*)d_in[0];
    const int*   root_nodes  = (const int*)  d_in[1];
    const float* root_biases = (const float*)d_in[2];
    // d_in[3] = tree_indices = 2*t, folded into index math
    const int*   nodes_flat  = (const int*)  d_in[4];
    const float* biases_flat = (const float*)d_in[5];
    const float* leaf_nodes  = (const float*)d_in[6];
    float*       out         = (float*)d_out;

    const bool packed = ws_size >= (size_t)NPACK * sizeof(int2);
    int2* tp = (int2*)d_ws;

    if (packed) {
        pack_nodes_kernel<<<(NPACK + 255) / 256, 256, 0, stream>>>(
            nodes_flat, biases_flat, tp, NPACK);
        tree_traverse_kernel<true><<<BB / S_, NT_, 0, stream>>>(
            x, root_nodes, root_biases, nodes_flat, biases_flat, leaf_nodes, tp, out);
    } else {
        tree_traverse_kernel<false><<<BB / S_, NT_, 0, stream>>>(
            x, root_nodes, root_biases, nodes_flat, biases_flat, leaf_nodes, tp, out);
    }
}